// Round 1
// baseline (403.436 us; speedup 1.0000x reference)
//
#include <hip/hip_runtime.h>
#include <hip/hip_bf16.h>
#include <stdint.h>

// Problem constants
constexpr int Bc = 8, Sc = 2048, Ec = 1024, Hc = 64;

typedef __bf16 bf16x8 __attribute__((ext_vector_type(8)));
typedef float f32x4 __attribute__((ext_vector_type(4)));
typedef unsigned short ushort8 __attribute__((ext_vector_type(8)));

static __device__ __forceinline__ unsigned short f2bf(float f) {
  uint32_t u = __builtin_bit_cast(uint32_t, f);
  u = u + 0x7fffu + ((u >> 16) & 1u);   // round-to-nearest-even
  return (unsigned short)(u >> 16);
}
static __device__ __forceinline__ bf16x8 ldb8(const unsigned short* p) {
  return __builtin_bit_cast(bf16x8, *(const ushort8*)p);
}

// ---------------------------------------------------------------------------
// Kernel 0: W [E,H] fp32 -> Wt [3][H][E] bf16  (so B-fragments read contiguous)
// ---------------------------------------------------------------------------
__global__ __launch_bounds__(256) void wt_kernel(
    const float* __restrict__ Wq, const float* __restrict__ Wk,
    const float* __restrict__ Wv, unsigned short* __restrict__ Wt) {
  int idx = blockIdx.x * 256 + threadIdx.x;        // 0 .. 3*64*1024
  int m = idx >> 16;                                // /65536
  int r = idx & 65535;
  int h = r >> 10;
  int e = r & 1023;
  const float* W = (m == 0) ? Wq : (m == 1) ? Wk : Wv;
  Wt[idx] = f2bf(W[e * Hc + h]);
}

// ---------------------------------------------------------------------------
// Kernel 1: projections. X [16384,1024] fp32 @ Wt^T -> bf16.
// block = 256 thr (4 waves); block tile = 64 rows x 64 cols; wave = 16 rows.
// Q,K stored row-major [s][h]; V stored transposed [b][h][s].
// ---------------------------------------------------------------------------
__global__ __launch_bounds__(256) void proj_kernel(
    const float* __restrict__ Xq, const float* __restrict__ Xk,
    const float* __restrict__ Xv, const float* __restrict__ bq,
    const float* __restrict__ bk, const float* __restrict__ bv,
    const unsigned short* __restrict__ Wt,
    unsigned short* __restrict__ Qb, unsigned short* __restrict__ Kb,
    unsigned short* __restrict__ Vt) {
  const int mat = blockIdx.y;
  const float* X = (mat == 0) ? Xq : (mat == 1) ? Xk : Xv;
  const float* bias = (mat == 0) ? bq : (mat == 1) ? bk : bv;
  const unsigned short* W = Wt + mat * (Hc * Ec);

  const int tid = threadIdx.x;
  const int wave = tid >> 6, lane = tid & 63;
  const int row0 = blockIdx.x * 64;
  const int arow = row0 + wave * 16 + (lane & 15);
  const int kofs = (lane >> 4) * 8;

  const float* aptr = X + (size_t)arow * Ec + kofs;

  f32x4 acc[4];
  for (int nt = 0; nt < 4; nt++) acc[nt] = (f32x4){0.f, 0.f, 0.f, 0.f};

  const unsigned short* wbase = W + (size_t)(lane & 15) * Ec + kofs;

  for (int kb = 0; kb < Ec; kb += 32) {
    float4 a0 = *(const float4*)(aptr + kb);
    float4 a1 = *(const float4*)(aptr + kb + 4);
    ushort8 au;
    au[0] = f2bf(a0.x); au[1] = f2bf(a0.y); au[2] = f2bf(a0.z); au[3] = f2bf(a0.w);
    au[4] = f2bf(a1.x); au[5] = f2bf(a1.y); au[6] = f2bf(a1.z); au[7] = f2bf(a1.w);
    bf16x8 afrag = __builtin_bit_cast(bf16x8, au);
#pragma unroll
    for (int nt = 0; nt < 4; nt++) {
      bf16x8 bfrag = ldb8(wbase + (size_t)(nt * 16) * Ec + kb);
      acc[nt] = __builtin_amdgcn_mfma_f32_16x16x32_bf16(afrag, bfrag, acc[nt], 0, 0, 0);
    }
  }

  // Epilogue: stage C tile (64 rows x 64 cols) into LDS, then coalesced store.
  __shared__ unsigned short tile[64][72];  // 72: 16B-aligned rows, bank spread
#pragma unroll
  for (int nt = 0; nt < 4; nt++) {
    float bv_ = bias[nt * 16 + (lane & 15)];
#pragma unroll
    for (int r = 0; r < 4; r++) {
      float v = acc[nt][r] + bv_;
      tile[wave * 16 + (lane >> 4) * 4 + r][nt * 16 + (lane & 15)] = f2bf(v);
    }
  }
  __syncthreads();

  if (mat < 2) {
    unsigned short* out = (mat == 0) ? Qb : Kb;
    int s_l = tid >> 2;
    int hs = (tid & 3) * 16;
    ushort8 v0 = *(const ushort8*)&tile[s_l][hs];
    ushort8 v1 = *(const ushort8*)&tile[s_l][hs + 8];
    unsigned short* dst = out + (size_t)(row0 + s_l) * Hc + hs;
    *(ushort8*)dst = v0;
    *(ushort8*)(dst + 8) = v1;
  } else {
    // V transposed: Vt[b][h][s]
    int h = tid >> 2;
    int ss = (tid & 3) * 16;
    int bb = row0 >> 11;                 // row0 / 2048 (block never straddles b)
    int sbase = (row0 & 2047) + ss;
    ushort8 v0, v1;
#pragma unroll
    for (int i = 0; i < 8; i++) {
      v0[i] = tile[ss + i][h];
      v1[i] = tile[ss + 8 + i][h];
    }
    unsigned short* dst = Vt + ((size_t)bb * Hc + h) * Sc + sbase;
    *(ushort8*)dst = v0;
    *(ushort8*)(dst + 8) = v1;
  }
}

// ---------------------------------------------------------------------------
// Kernel 2: flash-style attention with faithful mask->1e-10 semantics.
// grid (32,8): blockIdx.y=b, blockIdx.x=q-block of 64 rows. 4 waves x 16 q-rows.
// ---------------------------------------------------------------------------
__global__ __launch_bounds__(256) void attn_kernel(
    const unsigned short* __restrict__ Qb, const unsigned short* __restrict__ Kb,
    const unsigned short* __restrict__ Vt, const int* __restrict__ mask,
    float* __restrict__ out) {
  const int b = blockIdx.y;
  const int q0 = blockIdx.x * 64;
  const int tid = threadIdx.x;
  const int wave = tid >> 6, lane = tid & 63;

  __shared__ unsigned short Ks[64][72];       // [key][h]
  __shared__ unsigned short Vs[64][72];       // [h][key]
  __shared__ unsigned short Ps[4][16][72];    // per-wave P (A-layout staging)

  // Q A-fragments (fixed for whole K loop)
  const int qrow = q0 + wave * 16 + (lane & 15);
  const unsigned short* qptr = Qb + ((size_t)b * Sc + qrow) * Hc + (lane >> 4) * 8;
  bf16x8 aQ0 = ldb8(qptr);
  bf16x8 aQ1 = ldb8(qptr + 32);

  // online-softmax state; C-layout rows: qout_row + r
  const int qout_row = q0 + wave * 16 + (lane >> 4) * 4;
  float m_r[4], l_r[4];
  f32x4 Oacc[4];
#pragma unroll
  for (int r = 0; r < 4; r++) { m_r[r] = -INFINITY; l_r[r] = 0.f; }
#pragma unroll
  for (int ht = 0; ht < 4; ht++) Oacc[ht] = (f32x4){0.f, 0.f, 0.f, 0.f};

  const int* mbase[4];
#pragma unroll
  for (int r = 0; r < 4; r++)
    mbase[r] = mask + ((size_t)b * Sc + qout_row + r) * Sc + (lane & 15);

  for (int k0 = 0; k0 < Sc; k0 += 64) {
    __syncthreads();  // previous iteration's LDS reads done
    {
      int key = tid >> 2;
      int hs = (tid & 3) * 16;
      const unsigned short* kp = Kb + ((size_t)b * Sc + k0 + key) * Hc + hs;
      *(ushort8*)&Ks[key][hs] = *(const ushort8*)kp;
      *(ushort8*)&Ks[key][hs + 8] = *(const ushort8*)(kp + 8);
      const unsigned short* vp = Vt + ((size_t)b * Hc + key) * Sc + k0 + hs;
      *(ushort8*)&Vs[key][hs] = *(const ushort8*)vp;
      *(ushort8*)&Vs[key][hs + 8] = *(const ushort8*)(vp + 8);
    }
    __syncthreads();

    // S = Q @ K^T  (scale + mask applied per element)
    float sv[4][4];
#pragma unroll
    for (int nt = 0; nt < 4; nt++) {
      const unsigned short* kr = &Ks[nt * 16 + (lane & 15)][(lane >> 4) * 8];
      bf16x8 bK0 = ldb8(kr);
      bf16x8 bK1 = ldb8(kr + 32);
      f32x4 s = (f32x4){0.f, 0.f, 0.f, 0.f};
      s = __builtin_amdgcn_mfma_f32_16x16x32_bf16(aQ0, bK0, s, 0, 0, 0);
      s = __builtin_amdgcn_mfma_f32_16x16x32_bf16(aQ1, bK1, s, 0, 0, 0);
#pragma unroll
      for (int r = 0; r < 4; r++) {
        int mv = mbase[r][k0 + nt * 16];
        float x = s[r] * 0.125f;
        sv[nt][r] = mv ? 1e-10f : x;
      }
    }

    // row max across 4 n-tiles then across the 16-lane group
    float rmax[4];
#pragma unroll
    for (int r = 0; r < 4; r++) {
      rmax[r] = fmaxf(fmaxf(sv[0][r], sv[1][r]), fmaxf(sv[2][r], sv[3][r]));
#pragma unroll
      for (int off = 1; off < 16; off <<= 1)
        rmax[r] = fmaxf(rmax[r], __shfl_xor(rmax[r], off, 64));
    }

    float alpha[4], p[4][4], psum[4];
#pragma unroll
    for (int r = 0; r < 4; r++) {
      float mnew = fmaxf(m_r[r], rmax[r]);
      alpha[r] = __expf(m_r[r] - mnew);
      m_r[r] = mnew;
      psum[r] = 0.f;
    }
#pragma unroll
    for (int nt = 0; nt < 4; nt++)
#pragma unroll
      for (int r = 0; r < 4; r++) {
        p[nt][r] = __expf(sv[nt][r] - m_r[r]);
        psum[r] += p[nt][r];
      }
#pragma unroll
    for (int r = 0; r < 4; r++) {
#pragma unroll
      for (int off = 1; off < 16; off <<= 1)
        psum[r] += __shfl_xor(psum[r], off, 64);
      l_r[r] = l_r[r] * alpha[r] + psum[r];
    }
#pragma unroll
    for (int ht = 0; ht < 4; ht++)
#pragma unroll
      for (int r = 0; r < 4; r++) Oacc[ht][r] *= alpha[r];

    // P: C-layout -> LDS -> A-layout
#pragma unroll
    for (int nt = 0; nt < 4; nt++)
#pragma unroll
      for (int r = 0; r < 4; r++)
        Ps[wave][(lane >> 4) * 4 + r][nt * 16 + (lane & 15)] = f2bf(p[nt][r]);
    __syncthreads();  // ensures LDS write->read ordering (own wave's slice only)

    // O += P @ V
#pragma unroll
    for (int ks = 0; ks < 2; ks++) {
      bf16x8 aP = ldb8(&Ps[wave][lane & 15][ks * 32 + (lane >> 4) * 8]);
#pragma unroll
      for (int ht = 0; ht < 4; ht++) {
        bf16x8 bV = ldb8(&Vs[ht * 16 + (lane & 15)][ks * 32 + (lane >> 4) * 8]);
        Oacc[ht] = __builtin_amdgcn_mfma_f32_16x16x32_bf16(aP, bV, Oacc[ht], 0, 0, 0);
      }
    }
  }

  // epilogue: out[b][q][h] = O / l
#pragma unroll
  for (int ht = 0; ht < 4; ht++)
#pragma unroll
    for (int r = 0; r < 4; r++)
      out[((size_t)b * Sc + qout_row + r) * Hc + ht * 16 + (lane & 15)] =
          Oacc[ht][r] / l_r[r];
}

// ---------------------------------------------------------------------------
extern "C" void kernel_launch(void* const* d_in, const int* in_sizes, int n_in,
                              void* d_out, int out_size, void* d_ws, size_t ws_size,
                              hipStream_t stream) {
  const float* Xq = (const float*)d_in[0];
  const float* Xk = (const float*)d_in[1];
  const float* Xv = (const float*)d_in[2];
  const int* mask = (const int*)d_in[3];
  const float* Wq = (const float*)d_in[4];
  const float* bq = (const float*)d_in[5];
  const float* Wk = (const float*)d_in[6];
  const float* bk = (const float*)d_in[7];
  const float* Wv = (const float*)d_in[8];
  const float* bv = (const float*)d_in[9];

  unsigned short* Qb = (unsigned short*)d_ws;              // [16384][64] bf16
  unsigned short* Kb = Qb + (size_t)Bc * Sc * Hc;          // [16384][64] bf16
  unsigned short* Vt = Kb + (size_t)Bc * Sc * Hc;          // [8][64][2048] bf16
  unsigned short* Wt = Vt + (size_t)Bc * Sc * Hc;          // [3][64][1024] bf16

  wt_kernel<<<dim3(3 * Hc * Ec / 256), 256, 0, stream>>>(Wq, Wk, Wv, Wt);
  proj_kernel<<<dim3(Bc * Sc / 64, 3), 256, 0, stream>>>(Xq, Xk, Xv, bq, bk, bv,
                                                         Wt, Qb, Kb, Vt);
  attn_kernel<<<dim3(Sc / 64, Bc), 256, 0, stream>>>(Qb, Kb, Vt, mask,
                                                     (float*)d_out);
}